// Round 17
// baseline (457.692 us; speedup 1.0000x reference)
//
#include <hip/hip_runtime.h>
#include <hip/hip_bf16.h>
#include <math.h>

// NT-Xent loss, N=4096, D=256, symmetric-GEMM version.
// loss = (1/2N) * sum_i [ 2 + log( sum_{j != i} exp(2*dot_ij - 2) ) - 2*dot(zn_i, zn_pair(i)) ]
//
// ROUND-17 = r16 with the porting bug fixed: r16's colsum flush was lifted from
// r3's 512-thread kernel ("else if (tid<384)"), but this kernel runs 256
// threads -- columns 128..255 were never flushed (absmax 0.5). Now tid<128
// flushes rowsum + colsum half 0, tid>=128 flushes colsum half 1.
// Theory (r16): 128x256 tile at rendezvous WIDTH 4 -- wave computes 64x128
// (acc[4][8]), B-panel shared across 2x output. Staged bytes/output -24%,
// waves 8320->4224, blocks 2080->1056, width stays 4 (r13: width 8 = +11us).
// K1: 2048 blocks: normalize rows -> bf16 zn; zero rowtotal[8192] and out.
// K2: 1056 blocks x 256 thr: tiles (jbb,ib), ib in [0,2jbb+2); per-wave col
//     half jb_h = 2*jbb+wc with (valid,diag,pair) flags; r0 staging/swizzle;
//     parallel-scratch epilogue (r12/r15) with q*4 bank rotation; XCD swizzle.
// K3: 32 blocks: loss += sum_i (2 + log(rowtotal[i])) / 2N.

using short8  = __attribute__((ext_vector_type(8))) short;
using floatx4 = __attribute__((ext_vector_type(4))) float;

constexpr int TWO_N = 8192;
constexpr int DIM   = 256;
constexpr int NJB   = 32;                // 256-wide column blocks
constexpr int NBLK  = NJB * (NJB + 1);   // 1056 tiles
constexpr float INV2N = 1.0f / 8192.0f;

__device__ static inline unsigned short f2bf(float f) {
  unsigned u = __float_as_uint(f);
  return (unsigned short)((u + 0x7fffu + ((u >> 16) & 1u)) >> 16);  // RNE
}

__device__ static inline void async_copy16(const __hip_bfloat16* g, __hip_bfloat16* l) {
  __builtin_amdgcn_global_load_lds(
      (const __attribute__((address_space(1))) void*)(const void*)g,
      (__attribute__((address_space(3))) void*)(void*)l, 16, 0, 0);
}

// ---------------- K1: normalize + cast to bf16, zero accumulators ----------------
__global__ __launch_bounds__(256) void k_normalize(
    const float* __restrict__ zi, const float* __restrict__ zj,
    __hip_bfloat16* __restrict__ zn, float* __restrict__ rowtotal,
    float* __restrict__ out)
{
  if (blockIdx.x == 0 && threadIdx.x == 0) out[0] = 0.0f;
  if (blockIdx.x < 32) rowtotal[blockIdx.x * 256 + threadIdx.x] = 0.0f;

  const int lane = threadIdx.x & 63;
  const int wave = threadIdx.x >> 6;
  const int row  = blockIdx.x * 4 + wave;
  const float* src = (row < 4096) ? (zi + (size_t)row * DIM)
                                  : (zj + (size_t)(row - 4096) * DIM);
  float4 v = reinterpret_cast<const float4*>(src)[lane];
  float ss = v.x * v.x + v.y * v.y + v.z * v.z + v.w * v.w;
#pragma unroll
  for (int m = 32; m >= 1; m >>= 1) ss += __shfl_xor(ss, m, 64);
  float inv = 1.0f / fmaxf(sqrtf(ss), 1e-8f);
  ushort4 o;
  o.x = f2bf(v.x * inv); o.y = f2bf(v.y * inv);
  o.z = f2bf(v.z * inv); o.w = f2bf(v.w * inv);
  reinterpret_cast<ushort4*>(zn + (size_t)row * DIM)[lane] = o;
}

// ---------------- K2: width-4 128x256 triangular GEMM + parallel-scratch epilogue ----------------
// 4 waves: wm = wave>>1 (64-row half), wc = wave&1 (128-col half = jb block).
// Wave computes 64x128 = acc[4][8]. LDS S[384][64] bf16: rows 0-127 = A (ib),
// rows 128-383 = B (jbb pair). r0 16B-slot XOR swizzle per 8-row segment.
// C/D: col=c16 within nt-tile, row=q*4+reg within mt-tile. Tile-diag elem of
// wave's slab: global col == global row requires nt == wm*4+mt && c16==q*4+reg
// (col = wc*128+nt*16+c16, row = wm*64+mt*16+q*4+reg, jb_h==ib). Pair elems
// (jb_h==ib+32) at the same (nt,c16) condition since jb_h*128 = i0+4096.
__global__ __launch_bounds__(256) void k_simexp(
    const __hip_bfloat16* __restrict__ Z, float* __restrict__ rowtotal,
    float* __restrict__ out)
{
  __shared__ __align__(16) char smem[384 * 64 * 2];   // 48 KB: A|B, scratch overlay
  __shared__ float colsum[256];
  __hip_bfloat16* S = (__hip_bfloat16*)smem;
  float* scratch = (float*)smem;            // [128][33] f32 = 16.9 KB (tiles dead)

  const int tid  = threadIdx.x;
  const int lane = tid & 63;
  const int wave = tid >> 6;    // 0..3
  const int wm   = wave >> 1;   // 0..1: 64-row half
  const int wc   = wave & 1;    // 0..1: 128-col half

  // XCD-bijective chunked swizzle: 1056 = 8 * 132 (T1)
  const int bid = blockIdx.x;
  const int u   = (bid & 7) * (NBLK / 8) + (bid >> 3);

  // decode: u -> (jbb, ib), ib in [0, 2*jbb+2); cumulative C(j) = j*(j+1)
  int jbb = (int)((sqrtf(4.0f * (float)u + 1.0f) - 1.0f) * 0.5f);
  while ((jbb + 1) * (jbb + 2) <= u) ++jbb;
  while (jbb * (jbb + 1) > u) --jbb;
  const int ib = u - jbb * (jbb + 1);

  const int i0  = ib * 128;
  const int j00 = jbb * 256;
  const int jb_h = 2 * jbb + wc;          // this wave's 128-col block
  const bool valid   = (jb_h >= ib);      // false only for wc=0 when ib==2jbb+1
  const bool diagblk = (jb_h == ib);
  const bool pairblk = (jb_h == ib + 32);

  colsum[tid] = 0.0f;                     // all 256 columns

  floatx4 acc[4][8] = {};

  const int lane7 = lane & 7;
  const int sub   = lane >> 3;               // 0..7 subrow within 8-row copy
  const int gkoff = ((lane7 ^ sub) << 3);    // swizzled logical 16B slot to fetch
  const int q     = lane >> 4;               // 0..3
  const int c16   = lane & 15;

  for (int kk = 0; kk < 4; ++kk) {
    const int k0 = kk * 64;
    // stage 384 rows x 64 cols: 4 waves x 12 copies x 8 rows
#pragma unroll
    for (int c = 0; c < 12; ++c) {
      const int rrb  = wave * 96 + c * 8;            // wave-uniform LDS row base
      const int rr   = rrb + sub;                    // this lane's source row
      const int grow = (rr < 128) ? (i0 + rr) : (j00 + rr - 128);
      async_copy16(Z + (size_t)grow * DIM + k0 + gkoff, S + rrb * 64);
    }
    __syncthreads();

    const __hip_bfloat16* Bb = S + 128 * 64;
#pragma unroll
    for (int ks = 0; ks < 2; ++ks) {
      const int phys = (ks * 4 + q) ^ lane7;  // physical 16B slot for this lane
      short8 a[4];
#pragma unroll
      for (int mt = 0; mt < 4; ++mt)
        a[mt] = *reinterpret_cast<const short8*>(
            S + (wm * 64 + mt * 16 + c16) * 64 + phys * 8);
#pragma unroll
      for (int nh = 0; nh < 2; ++nh) {       // two nt-halves bound live b-frags
        short8 b[4];
#pragma unroll
        for (int j = 0; j < 4; ++j)
          b[j] = *reinterpret_cast<const short8*>(
              Bb + (wc * 128 + (nh * 4 + j) * 16 + c16) * 64 + phys * 8);
#pragma unroll
        for (int mt = 0; mt < 4; ++mt)
#pragma unroll
          for (int j = 0; j < 4; ++j)
            acc[mt][nh * 4 + j] = __builtin_amdgcn_mfma_f32_16x16x32_bf16(
                a[mt], b[j], acc[mt][nh * 4 + j], 0, 0, 0);
      }
    }
    __syncthreads();
  }

  // ---- epilogue (parallel-scratch, per-wave half flags) ----
  float colacc[8] = {0.f, 0.f, 0.f, 0.f, 0.f, 0.f, 0.f, 0.f};
  float rowacc[4][4];
  float pc = 0.f;

#pragma unroll
  for (int mt = 0; mt < 4; ++mt) {
#pragma unroll
    for (int reg = 0; reg < 4; ++reg) {
      const bool onquad = (c16 == q * 4 + reg);
      float s = 0.0f;
#pragma unroll
      for (int nt = 0; nt < 8; ++nt) {
        float e = __expf(2.0f * acc[mt][nt][reg] - 2.0f);
        bool skip = diagblk && onquad && (nt == wm * 4 + mt);  // true self-sim
        s += skip ? 0.0f : e;
        colacc[nt] += e;    // invalid/diag contamination never flushed below
      }
      if (pairblk && onquad) pc += acc[mt][wm * 4 + mt][reg];  // pair dot
      rowacc[mt][reg] = valid ? s : 0.0f;
    }
  }

  // column sums (only strictly-upper halves flush)
  if (jb_h > ib) {
#pragma unroll
    for (int nt = 0; nt < 8; ++nt) {
      float cs = colacc[nt];
      cs += __shfl_xor(cs, 16, 64);
      cs += __shfl_xor(cs, 32, 64);
      if (lane < 16) atomicAdd(&colsum[wc * 128 + nt * 16 + lane], cs);
    }
  }

  if (pairblk) {
#pragma unroll
    for (int m = 32; m >= 1; m >>= 1) pc += __shfl_xor(pc, m, 64);
    // each pair diag elem covers rows i and i+4096: loss += -2*(2*dot) per pair
    if (lane == 0) atomicAdd(out, -4.0f * pc * INV2N);
  }

  // row partials -> scratch[row][(wc*16+c16+q*4)&31] (q*4 rotation: write bank
  // = q*8+c16+const mod 32 -> every bank exactly 2x = free; reader sums the
  // whole row, so the within-row bijection is sum-invariant).
#pragma unroll
  for (int mt = 0; mt < 4; ++mt)
#pragma unroll
    for (int reg = 0; reg < 4; ++reg)
      scratch[(wm * 64 + mt * 16 + q * 4 + reg) * 33 +
              ((wc * 16 + c16 + q * 4) & 31)] = rowacc[mt][reg];

  __syncthreads();   // scratch writes + colsum atomics complete

  // FIXED FLUSH (r16 bug): 256 threads cover rowsum + BOTH 128-col halves.
  if (tid < 128) {
    float rs = 0.0f;
#pragma unroll
    for (int k = 0; k < 32; ++k) rs += scratch[tid * 33 + k];
    atomicAdd(&rowtotal[i0 + tid], rs);
    const int jb0 = 2 * jbb;
    if (jb0 > ib) atomicAdd(&rowtotal[jb0 * 128 + tid], colsum[tid]);
  } else {
    const int t   = tid - 128;             // 0..127: col within half 1
    const int jb1 = 2 * jbb + 1;
    if (jb1 > ib) atomicAdd(&rowtotal[jb1 * 128 + t], colsum[128 + t]);
  }
}

// ---------------- K3: finalize (logs + reduce) ----------------
__global__ __launch_bounds__(256) void k_finalize(
    const float* __restrict__ rowtotal, float* __restrict__ out)
{
  __shared__ float wsum[4];
  const int lane = threadIdx.x & 63;
  const int wave = threadIdx.x >> 6;
  const int row  = blockIdx.x * 256 + threadIdx.x;
  float v = 2.0f + __logf(rowtotal[row]);
#pragma unroll
  for (int m = 32; m >= 1; m >>= 1) v += __shfl_xor(v, m, 64);
  if (lane == 0) wsum[wave] = v;
  __syncthreads();
  if (threadIdx.x == 0)
    atomicAdd(out, (wsum[0] + wsum[1] + wsum[2] + wsum[3]) * INV2N);
}

// ---------------- launch ----------------
extern "C" void kernel_launch(void* const* d_in, const int* in_sizes, int n_in,
                              void* d_out, int out_size, void* d_ws, size_t ws_size,
                              hipStream_t stream) {
  const float* zi = (const float*)d_in[0];
  const float* zj = (const float*)d_in[1];
  float* out = (float*)d_out;

  __hip_bfloat16* zn = (__hip_bfloat16*)d_ws;                        // 8192*256*2 = 4 MB
  float* rowtotal = (float*)((char*)d_ws + (size_t)TWO_N * DIM * 2); // 8192*4 = 32 KB

  k_normalize<<<dim3(TWO_N / 4), dim3(256), 0, stream>>>(zi, zj, zn, rowtotal, out);
  k_simexp<<<dim3(NBLK), dim3(256), 0, stream>>>(zn, rowtotal, out);
  k_finalize<<<dim3(TWO_N / 256), dim3(256), 0, stream>>>(rowtotal, out);
}

// Round 18
// 87.054 us; speedup vs baseline: 5.2576x; 5.2576x over previous
//
#include <hip/hip_runtime.h>
#include <hip/hip_bf16.h>
#include <math.h>

// NT-Xent loss, N=4096, D=256, symmetric-GEMM version.
// loss = (1/2N) * sum_i [ 2 + log( sum_{j != i} exp(2*dot_ij - 2) ) - 2*dot(zn_i, zn_pair(i)) ]
//
// ROUND-18: restore the r15 champion (88.17 us, absmax 0.0) byte-for-byte.
// r16/r17 (width-4 128x256 tile) died of accumulator spill (acc[4][8] = 128
// f32/lane -> 1.8 GB scratch traffic, 398 us). With that, every structural
// axis of k_simexp is ablated: staging (DMA/reg/direct/fragment-major), tile
// (128^2 best), BK (64 best), sync (syncthreads best), grid (2080x1 best),
// waves (4 best), epilogue (parallel-scratch + q*4 rotation = the two real
// wins, -14 us and -2 us). Remaining budget: harness 268MB fill 43.5 us
// (inside timed window, untouchable) + k_simexp ~42.5 (latency-bound plateau,
// all pipes <25%) + norm ~2.5 + finalize ~1.5.
// K1: 2048 blocks: normalize rows -> bf16 zn; zero rowtotal[8192] and out.
// K2: 2080 upper-tri 128x128 tiles, 4 waves 2x2, r0 staging/swizzle/MFMA,
//     XCD-bijective swizzle, parallel-scratch epilogue with q*4 bank rotation.
// K3: 32 blocks: loss += sum_i (2 + log(rowtotal[i])) / 2N.

using short8  = __attribute__((ext_vector_type(8))) short;
using floatx4 = __attribute__((ext_vector_type(4))) float;

constexpr int TWO_N = 8192;
constexpr int DIM   = 256;
constexpr int NB    = 64;                 // 8192/128 tile blocks per side
constexpr int NTRI  = NB * (NB + 1) / 2;  // 2080
constexpr float INV2N = 1.0f / 8192.0f;

__device__ static inline unsigned short f2bf(float f) {
  unsigned u = __float_as_uint(f);
  return (unsigned short)((u + 0x7fffu + ((u >> 16) & 1u)) >> 16);  // RNE
}

__device__ static inline void async_copy16(const __hip_bfloat16* g, __hip_bfloat16* l) {
  __builtin_amdgcn_global_load_lds(
      (const __attribute__((address_space(1))) void*)(const void*)g,
      (__attribute__((address_space(3))) void*)(void*)l, 16, 0, 0);
}

// ---------------- K1: normalize + cast to bf16, zero accumulators ----------------
__global__ __launch_bounds__(256) void k_normalize(
    const float* __restrict__ zi, const float* __restrict__ zj,
    __hip_bfloat16* __restrict__ zn, float* __restrict__ rowtotal,
    float* __restrict__ out)
{
  if (blockIdx.x == 0 && threadIdx.x == 0) out[0] = 0.0f;
  if (blockIdx.x < 32) rowtotal[blockIdx.x * 256 + threadIdx.x] = 0.0f;

  const int lane = threadIdx.x & 63;
  const int wave = threadIdx.x >> 6;
  const int row  = blockIdx.x * 4 + wave;
  const float* src = (row < 4096) ? (zi + (size_t)row * DIM)
                                  : (zj + (size_t)(row - 4096) * DIM);
  float4 v = reinterpret_cast<const float4*>(src)[lane];
  float ss = v.x * v.x + v.y * v.y + v.z * v.z + v.w * v.w;
#pragma unroll
  for (int m = 32; m >= 1; m >>= 1) ss += __shfl_xor(ss, m, 64);
  float inv = 1.0f / fmaxf(sqrtf(ss), 1e-8f);
  ushort4 o;
  o.x = f2bf(v.x * inv); o.y = f2bf(v.y * inv);
  o.z = f2bf(v.z * inv); o.w = f2bf(v.w * inv);
  reinterpret_cast<ushort4*>(zn + (size_t)row * DIM)[lane] = o;
}

// ---------------- K2: triangular GEMM (r0) + parallel-scratch epilogue ----------------
// block 256 = 4 waves in 2x2; wave owns 64x64 (4x4 of 16x16x32 accumulators).
// LDS tiles [128][64] bf16 with 16B-slot XOR swizzle: phys_slot = logical ^ (row&7).
__global__ __launch_bounds__(256) void k_simexp(
    const __hip_bfloat16* __restrict__ Z, float* __restrict__ rowtotal,
    float* __restrict__ out)
{
  // 32 KB shared pool: As|Bs during the K-loop, scratch[128][33] f32 after.
  __shared__ __align__(16) char smem[128 * 64 * 2 * 2];
  __shared__ float colsum[128];
  __hip_bfloat16* As = (__hip_bfloat16*)smem;
  __hip_bfloat16* Bs = As + 128 * 64;
  float* scratch = (float*)smem;            // 128*33*4 = 16.9 KB <= 32 KB

  const int tid  = threadIdx.x;
  const int lane = tid & 63;
  const int wave = tid >> 6;
  const int wm   = wave >> 1;   // output row half
  const int wn   = wave & 1;    // output col half

  // XCD-bijective chunked swizzle: 2080 = 8 * 260 (T1; r10/r11 FETCH -27%)
  const int bid = blockIdx.x;
  const int u   = (bid & 7) * (NTRI / 8) + (bid >> 3);

  // triangular decode: u -> (ib <= jb)
  int jb = (int)((sqrtf(8.0f * (float)u + 1.0f) - 1.0f) * 0.5f);
  while ((jb + 1) * (jb + 2) / 2 <= u) ++jb;
  while (jb * (jb + 1) / 2 > u) --jb;
  const int ib = u - jb * (jb + 1) / 2;

  const bool diagblk = (ib == jb);
  const bool pairblk = (jb == ib + 32);
  const int i0 = ib * 128;
  const int j0 = jb * 128;

  if (tid < 128) colsum[tid] = 0.0f;

  floatx4 acc[4][4] = {};

  const int lane7 = lane & 7;
  const int sub   = lane >> 3;               // 0..7 subrow within 8-row segment
  const int gkoff = ((lane7 ^ sub) << 3);    // swizzled logical 16B slot to fetch
  const int q     = lane >> 4;               // 0..3
  const int c16   = lane & 15;

  // staging bases: waves 0,1 -> As (rows 0..63 / 64..127), waves 2,3 -> Bs
  const __hip_bfloat16* gbase =
      Z + (size_t)((wave < 2 ? i0 : j0) + (wave & 1) * 64) * DIM;
  __hip_bfloat16* lbase = ((wave < 2) ? As : Bs) + (wave & 1) * 64 * 64;

  for (int kk = 0; kk < 4; ++kk) {
    const int k0 = kk * 64;
#pragma unroll
    for (int c = 0; c < 8; ++c) {
      const __hip_bfloat16* gp = gbase + (size_t)(c * 8 + sub) * DIM + k0 + gkoff;
      async_copy16(gp, lbase + c * 512);   // + lane*16B implicit
    }
    __syncthreads();

#pragma unroll
    for (int ks = 0; ks < 2; ++ks) {
      const int phys = (ks * 4 + q) ^ lane7;  // physical 16B slot for this lane
      short8 a[4], b[4];
#pragma unroll
      for (int mt = 0; mt < 4; ++mt)
        a[mt] = *reinterpret_cast<const short8*>(
            As + (wm * 64 + mt * 16 + c16) * 64 + phys * 8);
#pragma unroll
      for (int nt = 0; nt < 4; ++nt)
        b[nt] = *reinterpret_cast<const short8*>(
            Bs + (wn * 64 + nt * 16 + c16) * 64 + phys * 8);
#pragma unroll
      for (int mt = 0; mt < 4; ++mt)
#pragma unroll
        for (int nt = 0; nt < 4; ++nt)
          acc[mt][nt] = __builtin_amdgcn_mfma_f32_16x16x32_bf16(
              a[mt], b[nt], acc[mt][nt], 0, 0, 0);
    }
    __syncthreads();
  }

  // ---- epilogue (parallel-scratch, r12-verified) ----
  // C/D layout: col = lane&15 (within nt-tile), row = q*4 + reg (within mt-tile).
  float colacc[4] = {0.f, 0.f, 0.f, 0.f};
  float rowacc[4][4];
  float pc = 0.f;
  const bool diagwave = (wm == wn);

#pragma unroll
  for (int mt = 0; mt < 4; ++mt) {
#pragma unroll
    for (int reg = 0; reg < 4; ++reg) {
      const bool onquad = (c16 == q * 4 + reg);  // lane holds a subtile-diag elem
      float s = 0.0f;
#pragma unroll
      for (int nt = 0; nt < 4; ++nt) {
        float e = __expf(2.0f * acc[mt][nt][reg] - 2.0f);
        bool skip = diagblk && diagwave && (nt == mt) && onquad;  // true self-sim
        s += skip ? 0.0f : e;
        colacc[nt] += e;    // diag contamination discarded (no colsum flush there)
      }
      if (pairblk && diagwave && onquad) pc += acc[mt][mt][reg];  // pair dot
      rowacc[mt][reg] = s;
    }
  }

  // column sums: reduce over the 4 q-groups (2 shfls), flush by lanes 0..15
  if (!diagblk) {
#pragma unroll
    for (int nt = 0; nt < 4; ++nt) {
      float cs = colacc[nt];
      cs += __shfl_xor(cs, 16, 64);
      cs += __shfl_xor(cs, 32, 64);
      if (lane < 16) atomicAdd(&colsum[wn * 64 + nt * 16 + lane], cs);
    }
  }

  if (pairblk && diagwave) {
#pragma unroll
    for (int m = 32; m >= 1; m >>= 1) pc += __shfl_xor(pc, m, 64);
    // each pair diag elem covers rows i and i+4096: loss += -2*(2*dot) per pair
    if (lane == 0) atomicAdd(out, -4.0f * pc * INV2N);
  }

  // row partials -> scratch[row][(wn*16+c16+q*4)&31]: q*4 rotation makes the
  // write bank (q*8+c16+const)%32 = every bank exactly 2x (2-way = free).
  // Reader sums all 32 entries of its row, so the rotation is sum-invariant.
#pragma unroll
  for (int mt = 0; mt < 4; ++mt)
#pragma unroll
    for (int reg = 0; reg < 4; ++reg)
      scratch[(wm * 64 + mt * 16 + q * 4 + reg) * 33 +
              ((wn * 16 + c16 + q * 4) & 31)] = rowacc[mt][reg];

  __syncthreads();   // scratch writes + colsum atomics complete

  if (tid < 128) {
    float rs = 0.0f;
#pragma unroll
    for (int k = 0; k < 32; ++k) rs += scratch[tid * 33 + k];
    atomicAdd(&rowtotal[i0 + tid], rs);
    if (!diagblk) atomicAdd(&rowtotal[j0 + tid], colsum[tid]);
  }
}

// ---------------- K3: finalize (logs + reduce) ----------------
__global__ __launch_bounds__(256) void k_finalize(
    const float* __restrict__ rowtotal, float* __restrict__ out)
{
  __shared__ float wsum[4];
  const int lane = threadIdx.x & 63;
  const int wave = threadIdx.x >> 6;
  const int row  = blockIdx.x * 256 + threadIdx.x;
  float v = 2.0f + __logf(rowtotal[row]);
#pragma unroll
  for (int m = 32; m >= 1; m >>= 1) v += __shfl_xor(v, m, 64);
  if (lane == 0) wsum[wave] = v;
  __syncthreads();
  if (threadIdx.x == 0)
    atomicAdd(out, (wsum[0] + wsum[1] + wsum[2] + wsum[3]) * INV2N);
}

// ---------------- launch ----------------
extern "C" void kernel_launch(void* const* d_in, const int* in_sizes, int n_in,
                              void* d_out, int out_size, void* d_ws, size_t ws_size,
                              hipStream_t stream) {
  const float* zi = (const float*)d_in[0];
  const float* zj = (const float*)d_in[1];
  float* out = (float*)d_out;

  __hip_bfloat16* zn = (__hip_bfloat16*)d_ws;                        // 8192*256*2 = 4 MB
  float* rowtotal = (float*)((char*)d_ws + (size_t)TWO_N * DIM * 2); // 8192*4 = 32 KB

  k_normalize<<<dim3(TWO_N / 4), dim3(256), 0, stream>>>(zi, zj, zn, rowtotal, out);
  k_simexp<<<dim3(NTRI), dim3(256), 0, stream>>>(zn, rowtotal, out);
  k_finalize<<<dim3(TWO_N / 256), dim3(256), 0, stream>>>(rowtotal, out);
}